// Round 11
// baseline (186.459 us; speedup 1.0000x reference)
//
#include <hip/hip_runtime.h>
#include <hip/hip_bf16.h>
#include <stdint.h>

#define NP 30000
#define BBINS 80
#define INCH 16
#define OUTCH 32
#define KDIM 1280       // BBINS*INCH
#define NDIM 512        // OUTCH*TBINS
#define KSTEPS 40       // KDIM/32
#define NROWS (NP * BBINS)   // 2,400,000
#define MTILES 235      // ceil(NP/128)

typedef __bf16 bf16x8 __attribute__((ext_vector_type(8)));
typedef __bf16 bf16x4 __attribute__((ext_vector_type(4)));
typedef float f32x4 __attribute__((ext_vector_type(4)));

__device__ __forceinline__ void async_ld16(const void* g, void* l) {
    __builtin_amdgcn_global_load_lds(
        (const __attribute__((address_space(1))) unsigned int*)g,
        (__attribute__((address_space(3))) unsigned int*)l,
        16, 0, 0);
}

// ---------------------------------------------------------------------------
// Prep: COMPACT weights wc[bid][o][c] bf16 (80*32*16 = 80KB). Rotation
// (b+5t)%80 realized as LDS addressing in gemm_max. (R10, refcheck-proven)
// ---------------------------------------------------------------------------
__global__ void prep_wc(const float* __restrict__ w, __bf16* __restrict__ wc) {
    int gid = blockIdx.x * 256 + threadIdx.x;            // 40960 total
    int c   = gid & 15;
    int o   = (gid >> 4) & 31;
    int bid = gid >> 9;                                  // 0..79
    wc[gid] = (__bf16)w[(bid * INCH + c) * OUTCH + o];
}

// ---------------------------------------------------------------------------
// Gather: verbatim R3 (57.6-60us proven).
// ---------------------------------------------------------------------------
__global__ __launch_bounds__(256) void gather_h(
    const float* __restrict__ x,
    const int*   __restrict__ cidx,
    const float* __restrict__ cval,
    __bf16* __restrict__ h) {
    const int gid = blockIdx.x * 256 + threadIdx.x;      // 9,600,000 total
    const int r = gid >> 2;                              // row 0..NROWS-1
    const int q = gid & 3;                               // channel quad
    const int r3 = r * 3;
    const int i0 = cidx[r3 + 0], i1 = cidx[r3 + 1], i2 = cidx[r3 + 2];
    const float v0 = cval[r3 + 0], v1 = cval[r3 + 1], v2 = cval[r3 + 2];
    const float4 a = *(const float4*)(x + (size_t)i0 * 16 + q * 4);
    const float4 b = *(const float4*)(x + (size_t)i1 * 16 + q * 4);
    const float4 c = *(const float4*)(x + (size_t)i2 * 16 + q * 4);
    bf16x4 hv;
    hv[0] = (__bf16)(v0 * a.x + v1 * b.x + v2 * c.x);
    hv[1] = (__bf16)(v0 * a.y + v1 * b.y + v2 * c.y);
    hv[2] = (__bf16)(v0 * a.z + v1 * b.z + v2 * c.z);
    hv[3] = (__bf16)(v0 * a.w + v1 * b.w + v2 * c.w);
    *(bf16x4*)((char*)h + (size_t)gid * 8) = hv;
}

// ---------------------------------------------------------------------------
// GEMM + max-over-t, LDS-resident compact B (R10, refcheck-proven) +
// DOUBLE-BUFFERED A with COUNTED vmcnt (T4).
// R10 diagnosis: removing all B staging left gemm at 57.5us -> the limiter
// is the per-kstep EXPOSED A-load latency: 1 block/CU (90KB LDS), and
// __syncthreads drains vmcnt(0), serializing ~600-900cy of h-load latency
// against ~310cy of MFMA every k-step (3450cy observed).
// Fix (the one R1 botched by draining vmcnt(0) after compute): per k-step
//   issue A(kc+1) -> buf^1 ; s_waitcnt vmcnt(1)  [A(kc) landed, A(kc+1)
//   IN FLIGHT] ; s_barrier ; ds_read+MFMA on buf[cur] ; s_barrier ; flip.
// The prefetch crosses the whole compute phase; vmcnt never drains to 0 in
// the main loop. Trailing barrier protects buf^1 from being overwritten
// while other waves still read it. Prologue Wlds fills are ordered by the
// same first vmcnt(1). sched_barrier(0) after the wait pins MFMA (rule #18).
// ---------------------------------------------------------------------------
__global__ __launch_bounds__(512, 1) void gemm_max(
    const __bf16* __restrict__ h,
    const __bf16* __restrict__ wc,
    float* __restrict__ out) {

    __shared__ __align__(16) __bf16 Wlds[80 * 32 * 16];  // 80 KB, swizzled
    __shared__ __align__(16) __bf16 Alds[2][128 * 32];   // 2 x 8 KB

    const int tid  = threadIdx.x;
    const int lane = tid & 63;
    const int wave = tid >> 6;           // 0..7
    const int wave_mrow = wave >> 2;     // 0..1
    const int wave_ncol = wave & 3;      // 0..3
    const int mbase = blockIdx.x * 128;

    // ---- one-time Wlds fill: 5120 x 16B chunks, 10/thread; linear dest +
    // involution-preswizzled source (XOR preserves bid bits >=10) ----
    {
        const char* src = (const char*)wc;
        char* dst = (char*)Wlds + tid * 16;
#pragma unroll
        for (int i = 0; i < 10; ++i) {
            const int byte = tid * 16 + i * 8192;
            const int bid  = byte >> 10;
            async_ld16(src + (byte ^ ((bid & 7) << 4)), dst + i * 8192);
        }
    }

    const int ml = lane & 15, q = lane >> 4;
    const int f  = (ml >> 1) & 3;
    int a_off[4];
#pragma unroll
    for (int i = 0; i < 4; ++i)
        a_off[i] = (wave_mrow * 64 + i * 16 + ml) * 64 + ((q ^ f) << 4);

    // B address state: addr_j = bid*1024 + (vj4[j] ^ ((bid&7)<<4)),
    // bid = (2kc + (q>>1) + 5*ml) % 80
    const int ch = q & 1;
    int vj4[8];
#pragma unroll
    for (int j = 0; j < 8; ++j) {
        const int o = wave_ncol * 8 + j;
        vj4[j] = (o * 2 + ch) << 4;
    }
    int bid = (q >> 1) + 5 * ml;         // kc=0 (< 80)

    f32x4 acc[4][8];
#pragma unroll
    for (int i = 0; i < 4; ++i)
#pragma unroll
        for (int j = 0; j < 8; ++j)
            acc[i][j] = (f32x4){0.f, 0.f, 0.f, 0.f};

    // A staging: row = tid>>2 (0..127), chunk = tid&3, pre-swizzled source
    int rg = mbase + (tid >> 2);
    if (rg > NP - 1) rg = NP - 1;
    const int swz = ((tid & 3) ^ ((tid >> 3) & 3)) * 16;
    const char* aSrc = (const char*)h + (size_t)rg * 2560 + swz;
    char* aDst0 = (char*)Alds + tid * 16;    // buf0 slot
    char* aDst1 = aDst0 + 8192;              // buf1 slot

    async_ld16(aSrc, aDst0);                 // prologue: A(0) -> buf0

    int cur = 0;
    for (int kc = 0; kc < KSTEPS; ++kc) {
        if (kc + 1 < KSTEPS) {
            async_ld16(aSrc + (kc + 1) * 64, cur ? aDst0 : aDst1);
            asm volatile("s_waitcnt vmcnt(1)" ::: "memory");
        } else {
            asm volatile("s_waitcnt vmcnt(0)" ::: "memory");
        }
        __builtin_amdgcn_s_barrier();        // all waves: buf[cur] ready
        __builtin_amdgcn_sched_barrier(0);   // rule #18: pin reads after wait

        const char* A = (const char*)Alds + cur * 8192;
        bf16x8 af[4], bfr[8];
#pragma unroll
        for (int i = 0; i < 4; ++i)
            af[i] = *(const bf16x8*)(A + a_off[i]);
        const int bidK = bid << 10;
        const int b74  = (bid & 7) << 4;
#pragma unroll
        for (int j = 0; j < 8; ++j)
            bfr[j] = *(const bf16x8*)((const char*)Wlds + (bidK + (vj4[j] ^ b74)));
#pragma unroll
        for (int i = 0; i < 4; ++i)
#pragma unroll
            for (int j = 0; j < 8; ++j)
                acc[i][j] = __builtin_amdgcn_mfma_f32_16x16x32_bf16(
                    af[i], bfr[j], acc[i][j], 0, 0, 0);

        __builtin_amdgcn_s_barrier();        // all waves done reading buf[cur]
        cur ^= 1;
        bid += 2;
        if (bid >= BBINS) bid -= BBINS;
    }

    const int rgrp = lane >> 4;
    const int tl   = lane & 15;
#pragma unroll
    for (int i = 0; i < 4; ++i) {
#pragma unroll
        for (int j = 0; j < 8; ++j) {
            float v0 = acc[i][j][0], v1 = acc[i][j][1];
            float v2 = acc[i][j][2], v3 = acc[i][j][3];
#pragma unroll
            for (int off = 1; off < 16; off <<= 1) {
                v0 = fmaxf(v0, __shfl_xor(v0, off));
                v1 = fmaxf(v1, __shfl_xor(v1, off));
                v2 = fmaxf(v2, __shfl_xor(v2, off));
                v3 = fmaxf(v3, __shfl_xor(v3, off));
            }
            if (tl == 0) {
                const int o  = wave_ncol * 8 + j;
                const int pr = mbase + wave_mrow * 64 + i * 16 + rgrp * 4;
                if (pr + 0 < NP) out[(pr + 0) * 32 + o] = v0;
                if (pr + 1 < NP) out[(pr + 1) * 32 + o] = v1;
                if (pr + 2 < NP) out[(pr + 2) * 32 + o] = v2;
                if (pr + 3 < NP) out[(pr + 3) * 32 + o] = v3;
            }
        }
    }
}

extern "C" void kernel_launch(void* const* d_in, const int* in_sizes, int n_in,
                              void* d_out, int out_size, void* d_ws, size_t ws_size,
                              hipStream_t stream) {
    const float* x    = (const float*)d_in[0];
    const int*   cidx = (const int*)d_in[1];
    const float* cval = (const float*)d_in[2];
    const float* w    = (const float*)d_in[3];
    float* out = (float*)d_out;

    __bf16* wc = (__bf16*)d_ws;                               // 80 KB compact
    __bf16* h  = (__bf16*)((char*)d_ws + (2 << 20));          // 76.8 MB @ +2MB

    hipLaunchKernelGGL(prep_wc, dim3(160), dim3(256), 0, stream, w, wc);
    hipLaunchKernelGGL(gather_h, dim3(NROWS * 4 / 256), dim3(256), 0, stream,
                       x, cidx, cval, h);
    hipLaunchKernelGGL(gemm_max, dim3(MTILES), dim3(512), 0, stream,
                       h, (const __bf16*)wc, out);
}

// Round 12
// 168.728 us; speedup vs baseline: 1.1051x; 1.1051x over previous
//
#include <hip/hip_runtime.h>
#include <hip/hip_bf16.h>
#include <stdint.h>

#define NP 30000
#define BBINS 80
#define INCH 16
#define OUTCH 32
#define KDIM 1280       // BBINS*INCH
#define NDIM 512        // OUTCH*TBINS
#define KSTEPS 40       // KDIM/32 (BK=32 = 2 bins)
#define MTILES 235      // ceil(NP/128)

typedef __bf16 bf16x8 __attribute__((ext_vector_type(8)));
typedef float f32x4 __attribute__((ext_vector_type(4)));

__device__ __forceinline__ void async_ld16(const void* g, void* l) {
    __builtin_amdgcn_global_load_lds(
        (const __attribute__((address_space(1))) unsigned int*)g,
        (__attribute__((address_space(3))) unsigned int*)l,
        16, 0, 0);
}

// ---------------------------------------------------------------------------
// Prep: COMPACT weights wc[bid][o][c] bf16 (80KB). Rotation (b+5t)%80 is
// realized as LDS addressing in the fused kernel. (R10/R11, refcheck-proven)
// ---------------------------------------------------------------------------
__global__ void prep_wc(const float* __restrict__ w, __bf16* __restrict__ wc) {
    int gid = blockIdx.x * 256 + threadIdx.x;            // 40960 total
    int c   = gid & 15;
    int o   = (gid >> 4) & 31;
    int bid = gid >> 9;                                  // 0..79
    wc[gid] = (__bf16)w[(bid * INCH + c) * OUTCH + o];
}

// ---------------------------------------------------------------------------
// FUSED gather + GEMM + max, B LDS-RESIDENT, RAW-BARRIER PIPELINE.
// Why R6/R8 fusion was flat: __syncthreads emits s_waitcnt vmcnt(0) -- it
// drained the x/meta prefetch issued the same step. Fixed here: raw
// s_barrier + lgkmcnt(0)-only waits; vmcnt is NEVER drained in the loop
// (T4), so x(kc+1)/meta(kc+2) fly across both barriers. B staging is gone
// entirely (R10: 80KB compact weights resident in Wlds, rotation in the
// read address) -- no B requests, no B drain, no LDS write contention.
// Per k-step critical path: hv VALU + ds_write + ds_read + 32 MFMA; the
// 7.2M x-gather L2 requests stream underneath at ~7 req/cy/XCD.
// Block: 512 thr, 128 patches x N=512, 8 waves (2M x 4N), wave 64x128 =
// proven 4x8 acc. Gather unit/thread: (patch_l=tid>>2, bin_l, half).
// All sub-pieces refcheck-proven in R8/R10/R11.
// ---------------------------------------------------------------------------
__global__ __launch_bounds__(512, 1) void fused_gemm_max(
    const float* __restrict__ x,
    const int*   __restrict__ cidx,
    const float* __restrict__ cval,
    const __bf16* __restrict__ wc,
    float* __restrict__ out) {

    __shared__ __align__(16) __bf16 Wlds[80 * 32 * 16];  // 80 KB, swizzled
    __shared__ __align__(16) __bf16 Alds[128 * 32];      // 8 KB

    const int tid  = threadIdx.x;
    const int lane = tid & 63;
    const int wave = tid >> 6;           // 0..7
    const int wave_mrow = wave >> 2;     // 0..1
    const int wave_ncol = wave & 3;      // 0..3
    const int mbase = blockIdx.x * 128;

    // ---- Wlds fill FIRST (oldest vmcnt entries; drained by the compiler's
    // wait for x(0) regs before the first barrier). Linear dest +
    // involution-preswizzled source (rule #21; R10-proven). ----
    {
        const char* src = (const char*)wc;
        char* dst = (char*)Wlds + tid * 16;
#pragma unroll
        for (int i = 0; i < 10; ++i) {
            const int byte = tid * 16 + i * 8192;
            const int bid  = byte >> 10;
            async_ld16(src + (byte ^ ((bid & 7) << 4)), dst + i * 8192);
        }
    }

    // ---- gather unit mapping (R8-proven) ----
    const int patch_l = tid >> 2;        // 0..127
    const int chunk   = tid & 3;
    const int bin_l   = chunk >> 1;
    const int half    = chunk & 1;
    int p = mbase + patch_l;
    if (p > NP - 1) p = NP - 1;
    const int row0 = p * BBINS + bin_l;  // +2 per kstep
    char* aW = (char*)Alds + patch_l * 64
             + ((chunk ^ ((patch_l >> 1) & 3)) << 4);

    // ---- MFMA offsets (proven) ----
    const int ml = lane & 15, q = lane >> 4;
    const int f  = (ml >> 1) & 3;
    int a_off[4];
#pragma unroll
    for (int i = 0; i < 4; ++i)
        a_off[i] = (wave_mrow * 64 + i * 16 + ml) * 64 + ((q ^ f) << 4);
    const int ch = q & 1;
    int vj4[8];
#pragma unroll
    for (int j = 0; j < 8; ++j) {
        const int o = wave_ncol * 8 + j;
        vj4[j] = (o * 2 + ch) << 4;
    }
    int bid = (q >> 1) + 5 * ml;         // (2kc + q>>1 + 5ml) % 80, kc=0

    f32x4 acc[4][8];
#pragma unroll
    for (int i = 0; i < 4; ++i)
#pragma unroll
        for (int j = 0; j < 8; ++j)
            acc[i][j] = (f32x4){0.f, 0.f, 0.f, 0.f};

    // ---- gather pipeline prologue: meta(0) -> a; x(0) -> xa; meta(1) -> b
    int r3 = row0 * 3;
    float va0 = cval[r3], va1 = cval[r3 + 1], va2 = cval[r3 + 2];
    int   ia0 = cidx[r3], ia1 = cidx[r3 + 1], ia2 = cidx[r3 + 2];
    const float* xp;
    xp = x + (size_t)(unsigned)ia0 * 16 + half * 8;
    float4 xa0 = *(const float4*)xp, xa1 = *(const float4*)(xp + 4);
    xp = x + (size_t)(unsigned)ia1 * 16 + half * 8;
    float4 xa2 = *(const float4*)xp, xa3 = *(const float4*)(xp + 4);
    xp = x + (size_t)(unsigned)ia2 * 16 + half * 8;
    float4 xa4 = *(const float4*)xp, xa5 = *(const float4*)(xp + 4);
    r3 = (row0 + 2) * 3;
    int   ib0 = cidx[r3], ib1 = cidx[r3 + 1], ib2 = cidx[r3 + 2];
    float vb0 = cval[r3], vb1 = cval[r3 + 1], vb2 = cval[r3 + 2];

    for (int kc = 0; kc < KSTEPS; ++kc) {
        // hv = pure VALU on preloaded x(kc); ds_write into Alds
        bf16x8 hv;
        hv[0] = (__bf16)(va0 * xa0.x + va1 * xa2.x + va2 * xa4.x);
        hv[1] = (__bf16)(va0 * xa0.y + va1 * xa2.y + va2 * xa4.y);
        hv[2] = (__bf16)(va0 * xa0.z + va1 * xa2.z + va2 * xa4.z);
        hv[3] = (__bf16)(va0 * xa0.w + va1 * xa2.w + va2 * xa4.w);
        hv[4] = (__bf16)(va0 * xa1.x + va1 * xa3.x + va2 * xa5.x);
        hv[5] = (__bf16)(va0 * xa1.y + va1 * xa3.y + va2 * xa5.y);
        hv[6] = (__bf16)(va0 * xa1.z + va1 * xa3.z + va2 * xa5.z);
        hv[7] = (__bf16)(va0 * xa1.w + va1 * xa3.w + va2 * xa5.w);
        *(bf16x8*)aW = hv;

        // issue x(kc+1) via meta(kc+1); issue meta(kc+2); NOT drained in-loop
        float4 nx0 = xa0, nx1 = xa1, nx2 = xa2, nx3 = xa3, nx4 = xa4, nx5 = xa5;
        if (kc + 1 < KSTEPS) {
            xp = x + (size_t)(unsigned)ib0 * 16 + half * 8;
            nx0 = *(const float4*)xp; nx1 = *(const float4*)(xp + 4);
            xp = x + (size_t)(unsigned)ib1 * 16 + half * 8;
            nx2 = *(const float4*)xp; nx3 = *(const float4*)(xp + 4);
            xp = x + (size_t)(unsigned)ib2 * 16 + half * 8;
            nx4 = *(const float4*)xp; nx5 = *(const float4*)(xp + 4);
        }
        int   ni0 = ib0, ni1 = ib1, ni2 = ib2;
        float nv0 = vb0, nv1 = vb1, nv2 = vb2;
        if (kc + 2 < KSTEPS) {
            r3 = (row0 + (kc + 2) * 2) * 3;
            ni0 = cidx[r3 + 0]; ni1 = cidx[r3 + 1]; ni2 = cidx[r3 + 2];
            nv0 = cval[r3 + 0]; nv1 = cval[r3 + 1]; nv2 = cval[r3 + 2];
        }

        asm volatile("s_waitcnt lgkmcnt(0)" ::: "memory"); // my ds_write done
        __builtin_amdgcn_s_barrier();                      // Alds (+Wlds @kc=0) ready
        __builtin_amdgcn_sched_barrier(0);                 // no hoist above barrier

        bf16x8 af[4], bfr[8];
#pragma unroll
        for (int i = 0; i < 4; ++i)
            af[i] = *(const bf16x8*)((const char*)Alds + a_off[i]);
        const int bidK = bid << 10;
        const int b74  = (bid & 7) << 4;
#pragma unroll
        for (int j = 0; j < 8; ++j)
            bfr[j] = *(const bf16x8*)((const char*)Wlds + (bidK + (vj4[j] ^ b74)));
#pragma unroll
        for (int i = 0; i < 4; ++i)
#pragma unroll
            for (int j = 0; j < 8; ++j)
                acc[i][j] = __builtin_amdgcn_mfma_f32_16x16x32_bf16(
                    af[i], bfr[j], acc[i][j], 0, 0, 0);

        asm volatile("s_waitcnt lgkmcnt(0)" ::: "memory"); // my ds_reads done
        __builtin_amdgcn_s_barrier();                      // all reads done
        __builtin_amdgcn_sched_barrier(0);

        // rotate pipeline registers
        va0 = vb0; va1 = vb1; va2 = vb2;
        xa0 = nx0; xa1 = nx1; xa2 = nx2; xa3 = nx3; xa4 = nx4; xa5 = nx5;
        ib0 = ni0; ib1 = ni1; ib2 = ni2;
        vb0 = nv0; vb1 = nv1; vb2 = nv2;
        bid += 2;
        if (bid >= BBINS) bid -= BBINS;
    }

    const int rgrp = lane >> 4;
    const int tl   = lane & 15;
#pragma unroll
    for (int i = 0; i < 4; ++i) {
#pragma unroll
        for (int j = 0; j < 8; ++j) {
            float v0 = acc[i][j][0], v1 = acc[i][j][1];
            float v2 = acc[i][j][2], v3 = acc[i][j][3];
#pragma unroll
            for (int off = 1; off < 16; off <<= 1) {
                v0 = fmaxf(v0, __shfl_xor(v0, off));
                v1 = fmaxf(v1, __shfl_xor(v1, off));
                v2 = fmaxf(v2, __shfl_xor(v2, off));
                v3 = fmaxf(v3, __shfl_xor(v3, off));
            }
            if (tl == 0) {
                const int o  = wave_ncol * 8 + j;
                const int pr = mbase + wave_mrow * 64 + i * 16 + rgrp * 4;
                if (pr + 0 < NP) out[(pr + 0) * 32 + o] = v0;
                if (pr + 1 < NP) out[(pr + 1) * 32 + o] = v1;
                if (pr + 2 < NP) out[(pr + 2) * 32 + o] = v2;
                if (pr + 3 < NP) out[(pr + 3) * 32 + o] = v3;
            }
        }
    }
}

extern "C" void kernel_launch(void* const* d_in, const int* in_sizes, int n_in,
                              void* d_out, int out_size, void* d_ws, size_t ws_size,
                              hipStream_t stream) {
    const float* x    = (const float*)d_in[0];
    const int*   cidx = (const int*)d_in[1];
    const float* cval = (const float*)d_in[2];
    const float* w    = (const float*)d_in[3];
    float* out = (float*)d_out;

    __bf16* wc = (__bf16*)d_ws;                               // 80 KB compact

    hipLaunchKernelGGL(prep_wc, dim3(160), dim3(256), 0, stream, w, wc);
    hipLaunchKernelGGL(fused_gemm_max, dim3(MTILES), dim3(512), 0, stream,
                       x, cidx, cval, (const __bf16*)wc, out);
}